// Round 1
// baseline (79.415 us; speedup 1.0000x reference)
//
#include <hip/hip_runtime.h>
#include <hip/hip_bf16.h>

// CORAL ordinal-regression loss, mean-reduced.
// loss[i,k] = max(x,0) - x*[t_i > k] + log1p(exp(-|x|)),  x = logits[i,k]
// out[0] = mean(loss)
//
// B = 262144 rows, KM1 = 100 thresholds. 100 floats/row = 400 B -> 16B aligned,
// so flat float4 loads never straddle a row boundary (25 quads per row).

#define NBLOCKS 2048
#define NTHREADS 256

__device__ __forceinline__ float coral_elem(float x, bool lvl) {
    // max(x,0) - x*lvl + log1p(exp(-|x|))
    float l = fmaxf(x, 0.0f);
    if (lvl) l -= x;
    l += log1pf(__expf(-fabsf(x)));
    return l;
}

__global__ __launch_bounds__(NTHREADS) void coral_partial_kernel(
    const float4* __restrict__ logits4,
    const int* __restrict__ targets,
    float* __restrict__ partials,
    int total_quads)
{
    float acc = 0.0f;
    const int stride = gridDim.x * blockDim.x;
    for (int j = blockIdx.x * blockDim.x + threadIdx.x; j < total_quads; j += stride) {
        const int row  = j / 25;          // magic-mul, no real divide
        const int quad = j - row * 25;
        const float4 x = logits4[j];
        const int t  = targets[row];
        const int kb = quad * 4;
        acc += coral_elem(x.x, t > kb);
        acc += coral_elem(x.y, t > kb + 1);
        acc += coral_elem(x.z, t > kb + 2);
        acc += coral_elem(x.w, t > kb + 3);
    }

    // wave64 butterfly reduce
    #pragma unroll
    for (int off = 32; off > 0; off >>= 1)
        acc += __shfl_down(acc, off, 64);

    __shared__ float s[NTHREADS / 64];
    const int lane = threadIdx.x & 63;
    const int wave = threadIdx.x >> 6;
    if (lane == 0) s[wave] = acc;
    __syncthreads();
    if (threadIdx.x == 0) {
        float b = 0.0f;
        #pragma unroll
        for (int w = 0; w < NTHREADS / 64; ++w) b += s[w];
        partials[blockIdx.x] = b;
    }
}

__global__ __launch_bounds__(NTHREADS) void coral_final_kernel(
    const float* __restrict__ partials,
    float* __restrict__ out,
    int n_partials,
    float inv_n)
{
    float acc = 0.0f;
    for (int i = threadIdx.x; i < n_partials; i += NTHREADS)
        acc += partials[i];

    #pragma unroll
    for (int off = 32; off > 0; off >>= 1)
        acc += __shfl_down(acc, off, 64);

    __shared__ float s[NTHREADS / 64];
    const int lane = threadIdx.x & 63;
    const int wave = threadIdx.x >> 6;
    if (lane == 0) s[wave] = acc;
    __syncthreads();
    if (threadIdx.x == 0) {
        float b = 0.0f;
        #pragma unroll
        for (int w = 0; w < NTHREADS / 64; ++w) b += s[w];
        out[0] = b * inv_n;
    }
}

extern "C" void kernel_launch(void* const* d_in, const int* in_sizes, int n_in,
                              void* d_out, int out_size, void* d_ws, size_t ws_size,
                              hipStream_t stream) {
    const float* logits  = (const float*)d_in[0];
    const int*   targets = (const int*)d_in[1];
    float* out = (float*)d_out;
    float* partials = (float*)d_ws;

    const int n_elems = in_sizes[0];            // B * KM1 = 26,214,400
    const int total_quads = n_elems / 4;        // 6,553,600
    const float inv_n = 1.0f / (float)n_elems;

    coral_partial_kernel<<<NBLOCKS, NTHREADS, 0, stream>>>(
        (const float4*)logits, targets, partials, total_quads);
    coral_final_kernel<<<1, NTHREADS, 0, stream>>>(
        partials, out, NBLOCKS, inv_n);
}

// Round 2
// 29.237 us; speedup vs baseline: 2.7163x; 2.7163x over previous
//
#include <hip/hip_runtime.h>
#include <hip/hip_bf16.h>

// CORAL ordinal-regression loss, mean-reduced.
// loss[i,k] = max(x,0) - x*[t_i > k] + log1p(exp(-|x|)),  x = logits[i,k]
//           = softplus( (t_i > k) ? -x : x )        (identity: |y| = |x|)
// softplus(y) = max(y,0) + log(1 + exp(-|y|))  via v_exp_f32 / v_log_f32.
// out[0] = mean(loss)
//
// B = 262144 rows, KM1 = 100. 100 floats/row = 400 B -> flat float4 loads
// never straddle a row boundary (25 quads per row).

#define NBLOCKS 2048
#define NTHREADS 256

__device__ __forceinline__ float coral_elem(float x, float absx, bool lvl) {
    // softplus(lvl ? -x : x) with hardware exp2/log2
    const float y = lvl ? -x : x;
    const float e = __expf(-absx);          // v_exp_f32 (+1 mul)
    return fmaxf(y, 0.0f) + __logf(1.0f + e);  // v_log_f32 (+1 mul)
}

__global__ __launch_bounds__(NTHREADS) void coral_partial_kernel(
    const float4* __restrict__ logits4,
    const int* __restrict__ targets,
    float* __restrict__ partials,
    int total_quads)
{
    float acc = 0.0f;
    const int stride = gridDim.x * blockDim.x;
    for (int j = blockIdx.x * blockDim.x + threadIdx.x; j < total_quads; j += stride) {
        const int row  = j / 25;          // magic-mul, no real divide
        const int quad = j - row * 25;
        const float4 x = logits4[j];
        const int t  = targets[row];
        const int kb = quad * 4;
        acc += coral_elem(x.x, fabsf(x.x), t > kb);
        acc += coral_elem(x.y, fabsf(x.y), t > kb + 1);
        acc += coral_elem(x.z, fabsf(x.z), t > kb + 2);
        acc += coral_elem(x.w, fabsf(x.w), t > kb + 3);
    }

    // wave64 butterfly reduce
    #pragma unroll
    for (int off = 32; off > 0; off >>= 1)
        acc += __shfl_down(acc, off, 64);

    __shared__ float s[NTHREADS / 64];
    const int lane = threadIdx.x & 63;
    const int wave = threadIdx.x >> 6;
    if (lane == 0) s[wave] = acc;
    __syncthreads();
    if (threadIdx.x == 0) {
        float b = 0.0f;
        #pragma unroll
        for (int w = 0; w < NTHREADS / 64; ++w) b += s[w];
        partials[blockIdx.x] = b;
    }
}

__global__ __launch_bounds__(NTHREADS) void coral_final_kernel(
    const float* __restrict__ partials,
    float* __restrict__ out,
    int n_partials,
    float inv_n)
{
    float acc = 0.0f;
    for (int i = threadIdx.x; i < n_partials; i += NTHREADS)
        acc += partials[i];

    #pragma unroll
    for (int off = 32; off > 0; off >>= 1)
        acc += __shfl_down(acc, off, 64);

    __shared__ float s[NTHREADS / 64];
    const int lane = threadIdx.x & 63;
    const int wave = threadIdx.x >> 6;
    if (lane == 0) s[wave] = acc;
    __syncthreads();
    if (threadIdx.x == 0) {
        float b = 0.0f;
        #pragma unroll
        for (int w = 0; w < NTHREADS / 64; ++w) b += s[w];
        out[0] = b * inv_n;
    }
}

extern "C" void kernel_launch(void* const* d_in, const int* in_sizes, int n_in,
                              void* d_out, int out_size, void* d_ws, size_t ws_size,
                              hipStream_t stream) {
    const float* logits  = (const float*)d_in[0];
    const int*   targets = (const int*)d_in[1];
    float* out = (float*)d_out;
    float* partials = (float*)d_ws;

    const int n_elems = in_sizes[0];            // B * KM1 = 26,214,400
    const int total_quads = n_elems / 4;        // 6,553,600
    const float inv_n = 1.0f / (float)n_elems;

    coral_partial_kernel<<<NBLOCKS, NTHREADS, 0, stream>>>(
        (const float4*)logits, targets, partials, total_quads);
    coral_final_kernel<<<1, NTHREADS, 0, stream>>>(
        partials, out, NBLOCKS, inv_n);
}